// Round 2
// baseline (4026.197 us; speedup 1.0000x reference)
//
#include <hip/hip_runtime.h>
#include <hip/hip_bf16.h>

// FastKANLayer as one bf16 MFMA GEMM:
//   out[b,j] = A[b, i*36+c] @ Wb[i*36+c, j]
//   c<35: A = cubic B-spline basis (4-tap sparse), Wb = spline_weight[i,j,c]
//   c==35: A = silu(clip(x)),                      Wb = base_scale[i,j]
// M=4096, N=1024, K=36864. Tile 128x128x32, 4 waves.
// R2: NSPLIT=8 (occupancy was grid-limited at 44%), W staged via
// global_load_lds width=16 into unpadded Ws (64B row stride = free 2-way alias).

#define IN_DIM 1024
#define OUT_DIM 1024
#define NC 35
#define KPI 36
#define KTOT (IN_DIM * KPI)      // 36864
#define MROWS 4096
#define BM 128
#define BN 128
#define BK 32
#define BKPA 40                  // As padded row (80B stride keeps b128 16B-aligned)
#define BKW 32                   // Ws unpadded (global_load_lds needs contiguous lane order)
#define NSPLIT 8
#define KCH (KTOT / NSPLIT)      // 4608
#define NSTEP (KCH / BK)         // 144

typedef __attribute__((ext_vector_type(8))) __bf16 bf16x8;
typedef __attribute__((ext_vector_type(4))) float f32x4;

__device__ __forceinline__ unsigned short f2bf(float f) {
  unsigned int u = __builtin_bit_cast(unsigned int, f);
  u = (u + 0x7FFFu + ((u >> 16) & 1u)) >> 16;   // RNE
  return (unsigned short)u;
}

// ---- prep: Wb[n][k] bf16, k = i*36 + c (c fastest). 75.5 MB in d_ws. ----
__global__ __launch_bounds__(256) void prep_wb(const float* __restrict__ sw,
                                               const float* __restrict__ bs,
                                               unsigned short* __restrict__ wb) {
  int id = blockIdx.x * 256 + threadIdx.x;       // over OUT_DIM*IN_DIM (n,i) pairs
  int i = id & (IN_DIM - 1);
  int n = id >> 10;
  const float* s = sw + (size_t)i * (OUT_DIM * NC) + (size_t)n * NC;
  unsigned short v[KPI];
#pragma unroll
  for (int c = 0; c < NC; ++c) v[c] = f2bf(s[c]);
  v[NC] = f2bf(bs[(size_t)i * OUT_DIM + n]);
  uint2* dst = (uint2*)(wb + (size_t)n * KTOT + (size_t)i * KPI);  // 8B aligned
#pragma unroll
  for (int w = 0; w < 9; ++w) {
    uint2 t;
    t.x = (unsigned)v[4 * w + 0] | ((unsigned)v[4 * w + 1] << 16);
    t.y = (unsigned)v[4 * w + 2] | ((unsigned)v[4 * w + 3] << 16);
    dst[w] = t;
  }
}

template <bool USE_WB>
__global__ __launch_bounds__(256, 8) void kan_gemm(const float* __restrict__ x,
                                                   const unsigned short* __restrict__ wb,
                                                   const float* __restrict__ sw,
                                                   const float* __restrict__ bs,
                                                   float* __restrict__ out) {
  __shared__ __align__(16) unsigned short As[BM * BKPA];
  __shared__ __align__(16) unsigned short Ws[BN * BKW];

  const int tid = threadIdx.x;
  const int mt = blockIdx.x, nt = blockIdx.y, kc = blockIdx.z;

  // A staging ownership: thread owns row sb, k-halfwindow [klo, klo+16)
  const int sb = tid & 127;
  const int shalf = tid >> 7;
  const int klo = shalf * 16;
  // wave/fragment ids
  const int lane = tid & 63;
  const int wid = tid >> 6;
  const int wm = (wid & 1) * 64;
  const int wn = (wid >> 1) * 64;
  const int lm = lane & 15;
  const int quad = lane >> 4;
  const int ko = quad * 8;

  // W async-staging lane mapping: wave wid stages rows [wid*32, wid*32+32)
  const int wr16 = lane >> 2;         // row within 16-row chunk
  const int wkof = (lane & 3) * 8;    // k offset in ushorts (16B per lane)

  f32x4 acc[4][4];
#pragma unroll
  for (int a = 0; a < 4; ++a)
#pragma unroll
    for (int b = 0; b < 4; ++b) acc[a][b] = f32x4{0.f, 0.f, 0.f, 0.f};

  const float* xrow = x + (size_t)(mt * BM + sb) * IN_DIM;

  for (int step = 0; step < NSTEP; ++step) {
    const int kbase = kc * KCH + step * BK;

    // ---- zero my A half-row (same thread scatters into it: no barrier needed)
    {
      uint4 z = make_uint4(0, 0, 0, 0);
      uint4* az = (uint4*)(&As[sb * BKPA + klo]);
      az[0] = z;
      az[1] = z;
    }

    // ---- stage W tile [BN][BK] via async global->LDS (bf16, 16B/lane)
    if (USE_WB) {
#pragma unroll
      for (int c = 0; c < 2; ++c) {
        const int rbase = wid * 32 + c * 16;
        const unsigned short* g =
            wb + (size_t)(nt * BN + rbase + wr16) * KTOT + kbase + wkof;
        __builtin_amdgcn_global_load_lds(
            (const __attribute__((address_space(1))) unsigned int*)g,
            (__attribute__((address_space(3))) unsigned int*)(&Ws[rbase * BKW]),
            16, 0, 0);
      }
    } else {
      const int wrow = tid >> 1;
      const int whal = tid & 1;
      const int j = nt * BN + wrow;
      unsigned int p[8];
#pragma unroll
      for (int q = 0; q < 8; ++q) {
        unsigned int lohi = 0;
#pragma unroll
        for (int h = 0; h < 2; ++h) {
          int k = kbase + whal * 16 + q * 2 + h;
          int i = k / KPI;
          int c = k - i * KPI;
          float v = (c < NC) ? sw[(size_t)i * (OUT_DIM * NC) + (size_t)j * NC + c]
                             : bs[(size_t)i * OUT_DIM + j];
          lohi |= ((unsigned int)f2bf(v)) << (16 * h);
        }
        p[q] = lohi;
      }
      uint4* wd = (uint4*)(&Ws[wrow * BKW + whal * 16]);
      wd[0] = make_uint4(p[0], p[1], p[2], p[3]);
      wd[1] = make_uint4(p[4], p[5], p[6], p[7]);
    }

    // ---- scatter the 4 B-spline taps + base slot for the 1-2 i's in this K-window
    {
      const int ilo = kbase / KPI;
      const int ihi = (kbase + BK - 1) / KPI;
      for (int ii = ilo; ii <= ihi; ++ii) {
        float xv = xrow[ii];
        float xn = fminf(fmaxf(xv, -0.99f), 0.99f);
        float u = (xn + 1.0f) * 17.0f;     // 1/h = 17
        float sf = floorf(u);
        int s = (int)sf;
        float f = u - sf, g = 1.0f - f;
        float f2 = f * f, g2 = g * g;
        float v0 = g2 * g * (1.f / 6.f);
        float v1 = 0.66666667f - f2 + 0.5f * f2 * f;
        float v2 = 0.66666667f - g2 + 0.5f * g2 * g;
        float v3 = f2 * f * (1.f / 6.f);
        float sig = xn / (1.0f + __expf(-xn));
        const int kb0 = ii * KPI - kbase;  // rel k of (ii, c=0)
#pragma unroll
        for (int t = 0; t < 4; ++t) {
          int c = s - 1 + t;
          float v = (t == 0) ? v0 : (t == 1) ? v1 : (t == 2) ? v2 : v3;
          int kq = kb0 + c;
          if (c >= 0 && c < NC && kq >= klo && kq < klo + 16)
            As[sb * BKPA + kq] = f2bf(v);
        }
        int kqb = kb0 + NC;
        if (kqb >= klo && kqb < klo + 16) As[sb * BKPA + kqb] = f2bf(sig);
      }
    }

    __syncthreads();

    // ---- fragments + 16 MFMA
    uint4 af[4], bfr[4];
#pragma unroll
    for (int mi = 0; mi < 4; ++mi)
      af[mi] = *(const uint4*)(&As[(wm + mi * 16 + lm) * BKPA + ko]);
#pragma unroll
    for (int ni = 0; ni < 4; ++ni)
      bfr[ni] = *(const uint4*)(&Ws[(wn + ni * 16 + lm) * BKW + ko]);
#pragma unroll
    for (int mi = 0; mi < 4; ++mi)
#pragma unroll
      for (int ni = 0; ni < 4; ++ni)
        acc[mi][ni] = __builtin_amdgcn_mfma_f32_16x16x32_bf16(
            __builtin_bit_cast(bf16x8, af[mi]), __builtin_bit_cast(bf16x8, bfr[ni]),
            acc[mi][ni], 0, 0, 0);

    __syncthreads();
  }

  // ---- epilogue: C/D layout col=lane&15, row=quad*4+reg; split-K partials via atomics
#pragma unroll
  for (int mi = 0; mi < 4; ++mi)
#pragma unroll
    for (int ni = 0; ni < 4; ++ni)
#pragma unroll
      for (int r = 0; r < 4; ++r) {
        int row = mt * BM + wm + mi * 16 + quad * 4 + r;
        int col = nt * BN + wn + ni * 16 + lm;
        atomicAdd(&out[(size_t)row * OUT_DIM + col], acc[mi][ni][r]);
      }
}

extern "C" void kernel_launch(void* const* d_in, const int* in_sizes, int n_in,
                              void* d_out, int out_size, void* d_ws, size_t ws_size,
                              hipStream_t stream) {
  const float* x = (const float*)d_in[0];
  const float* sw = (const float*)d_in[1];
  const float* bs = (const float*)d_in[2];
  float* out = (float*)d_out;

  hipMemsetAsync(d_out, 0, (size_t)MROWS * OUT_DIM * sizeof(float), stream);

  const size_t WB_BYTES = (size_t)OUT_DIM * KTOT * sizeof(unsigned short);  // 75.5 MB
  dim3 grid(MROWS / BM, OUT_DIM / BN, NSPLIT);
  if (ws_size >= WB_BYTES) {
    unsigned short* wbp = (unsigned short*)d_ws;
    prep_wb<<<(IN_DIM * OUT_DIM) / 256, 256, 0, stream>>>(sw, bs, wbp);
    kan_gemm<true><<<grid, 256, 0, stream>>>(x, wbp, sw, bs, out);
  } else {
    kan_gemm<false><<<grid, 256, 0, stream>>>(x, nullptr, sw, bs, out);
  }
}

// Round 3
// 854.654 us; speedup vs baseline: 4.7109x; 4.7109x over previous
//
#include <hip/hip_runtime.h>
#include <hip/hip_bf16.h>

// FastKANLayer as one bf16 MFMA GEMM: out[b,j] = A[b,k] @ Wb[k,j], k = i*36+c.
//   c<35: A = cubic B-spline basis (4-tap sparse), Wb = spline_weight[i,j,c]
//   c==35: A = silu(clip(x)),                      Wb = base_scale[i,j]
// M=4096, N=1024, K=36864.
// R3: precompute A to global bf16 (302 MB in d_ws) -> GEMM K-loop is pure
// m97 structure (global_load_lds x4, 16 MFMA, 2 barriers; zero scatter VALU).
// R2 lesson: NO __launch_bounds__ min-waves — (256,8) spilled the 64-reg
// accumulator to scratch (WRITE_SIZE 65MB->9.5GB). Occupancy is register-
// limited at 4 waves/EU; grid 1024 blocks matches it exactly.

#define IN_DIM 1024
#define OUT_DIM 1024
#define NC 35
#define KPI 36
#define KTOT (IN_DIM * KPI)      // 36864
#define MROWS 4096
#define BM 128
#define BN 128
#define BK 32
#define NSPLIT 4
#define KCH (KTOT / NSPLIT)      // 9216
#define NSTEP (KCH / BK)         // 288

// fallback (R1) uses padded As for its in-kernel scatter
#define BKPA 40

typedef __attribute__((ext_vector_type(8))) __bf16 bf16x8;
typedef __attribute__((ext_vector_type(4))) float f32x4;

__device__ __forceinline__ unsigned short f2bf(float f) {
  unsigned int u = __builtin_bit_cast(unsigned int, f);
  u = (u + 0x7FFFu + ((u >> 16) & 1u)) >> 16;   // RNE
  return (unsigned short)u;
}

// ---- prep: Wb[n][k] bf16, k = i*36 + c (c fastest). 75.5 MB. ----
__global__ __launch_bounds__(256) void prep_wb(const float* __restrict__ sw,
                                               const float* __restrict__ bs,
                                               unsigned short* __restrict__ wb) {
  int id = blockIdx.x * 256 + threadIdx.x;       // over (n,i) pairs
  int i = id & (IN_DIM - 1);
  int n = id >> 10;
  const float* s = sw + (size_t)i * (OUT_DIM * NC) + (size_t)n * NC;
  unsigned short v[KPI];
#pragma unroll
  for (int c = 0; c < NC; ++c) v[c] = f2bf(s[c]);
  v[NC] = f2bf(bs[(size_t)i * OUT_DIM + n]);
  uint2* dst = (uint2*)(wb + (size_t)n * KTOT + (size_t)i * KPI);  // 8B aligned
#pragma unroll
  for (int w = 0; w < 9; ++w) {
    uint2 t;
    t.x = (unsigned)v[4 * w + 0] | ((unsigned)v[4 * w + 1] << 16);
    t.y = (unsigned)v[4 * w + 2] | ((unsigned)v[4 * w + 3] << 16);
    dst[w] = t;
  }
}

// ---- prep: A[b][k] bf16 basis matrix, 302 MB. One thread per (b,i): zero 36
// slots, scatter 4 taps + base into LDS row, then coalesced uint2 copy out. ----
__global__ __launch_bounds__(256) void prep_a(const float* __restrict__ x,
                                              unsigned short* __restrict__ A) {
  __shared__ unsigned short buf[256 * KPI];      // 18432 B
  const int tid = threadIdx.x;
  const int id = blockIdx.x * 256 + tid;         // (b,i): b=id>>10, i=id&1023
  float xv = x[id];                              // x is row-major [b][i] = flat id
  float xn = fminf(fmaxf(xv, -0.99f), 0.99f);
  float u = (xn + 1.0f) * 17.0f;                 // 1/h = 17
  float sf = floorf(u);
  int s = (int)sf;
  float f = u - sf, g = 1.0f - f;
  float f2 = f * f, g2 = g * g;
  float v0 = g2 * g * (1.f / 6.f);
  float v1 = 0.66666667f - f2 + 0.5f * f2 * f;
  float v2 = 0.66666667f - g2 + 0.5f * g2 * g;
  float v3 = f2 * f * (1.f / 6.f);
  float sig = xn / (1.0f + __expf(-xn));

  unsigned short* row = buf + tid * KPI;
  uint2 z = make_uint2(0, 0);
  uint2* rz = (uint2*)row;
#pragma unroll
  for (int w = 0; w < 9; ++w) rz[w] = z;
  // scatter (own row: no barrier needed between zero and scatter)
#pragma unroll
  for (int t = 0; t < 4; ++t) {
    int c = s - 1 + t;
    float v = (t == 0) ? v0 : (t == 1) ? v1 : (t == 2) ? v2 : v3;
    if (c >= 0 && c < NC) row[c] = f2bf(v);
  }
  row[NC] = f2bf(sig);
  __syncthreads();
  // block's region of A is contiguous: 256*36 ushorts = 2304 uint2
  uint2* gdst = (uint2*)(A + (size_t)blockIdx.x * (256 * KPI));
  const uint2* gsrc = (const uint2*)buf;
#pragma unroll
  for (int w = 0; w < 9; ++w) gdst[tid + w * 256] = gsrc[tid + w * 256];
}

// ---- fast GEMM: pure m97 structure, both tiles via global_load_lds. ----
__global__ __launch_bounds__(256) void kan_gemm_pre(const unsigned short* __restrict__ A,
                                                    const unsigned short* __restrict__ wb,
                                                    float* __restrict__ out) {
  __shared__ __align__(16) unsigned short As[BM * BK];   // 8 KB, unpadded
  __shared__ __align__(16) unsigned short Ws[BN * BK];   // 8 KB, unpadded

  const int tid = threadIdx.x;
  const int mt = blockIdx.x, nt = blockIdx.y, kc = blockIdx.z;

  const int lane = tid & 63;
  const int wid = tid >> 6;
  const int wm = (wid & 1) * 64;
  const int wn = (wid >> 1) * 64;
  const int lm = lane & 15;
  const int quad = lane >> 4;
  const int ko = quad * 8;

  // staging lane mapping: one global_load_lds covers 16 rows x 32 k (1 KB)
  const int wr16 = lane >> 2;          // row within 16-row chunk
  const int wkof = (lane & 3) * 8;     // k offset in ushorts (16 B / lane)

  f32x4 acc[4][4];
#pragma unroll
  for (int a = 0; a < 4; ++a)
#pragma unroll
    for (int b = 0; b < 4; ++b) acc[a][b] = f32x4{0.f, 0.f, 0.f, 0.f};

  const unsigned short* Abase =
      A + (size_t)(mt * BM + wid * 32 + wr16) * KTOT + kc * KCH + wkof;
  const unsigned short* Wbase =
      wb + (size_t)(nt * BN + wid * 32 + wr16) * KTOT + kc * KCH + wkof;

  for (int step = 0; step < NSTEP; ++step) {
    const int kof = step * BK;
#pragma unroll
    for (int c = 0; c < 2; ++c) {
      __builtin_amdgcn_global_load_lds(
          (const __attribute__((address_space(1))) unsigned int*)(Abase + (size_t)c * 16 * KTOT + kof),
          (__attribute__((address_space(3))) unsigned int*)(&As[(wid * 32 + c * 16) * BK]),
          16, 0, 0);
    }
#pragma unroll
    for (int c = 0; c < 2; ++c) {
      __builtin_amdgcn_global_load_lds(
          (const __attribute__((address_space(1))) unsigned int*)(Wbase + (size_t)c * 16 * KTOT + kof),
          (__attribute__((address_space(3))) unsigned int*)(&Ws[(wid * 32 + c * 16) * BK]),
          16, 0, 0);
    }
    __syncthreads();

    uint4 af[4], bfr[4];
#pragma unroll
    for (int mi = 0; mi < 4; ++mi)
      af[mi] = *(const uint4*)(&As[(wm + mi * 16 + lm) * BK + ko]);
#pragma unroll
    for (int ni = 0; ni < 4; ++ni)
      bfr[ni] = *(const uint4*)(&Ws[(wn + ni * 16 + lm) * BK + ko]);
#pragma unroll
    for (int mi = 0; mi < 4; ++mi)
#pragma unroll
      for (int ni = 0; ni < 4; ++ni)
        acc[mi][ni] = __builtin_amdgcn_mfma_f32_16x16x32_bf16(
            __builtin_bit_cast(bf16x8, af[mi]), __builtin_bit_cast(bf16x8, bfr[ni]),
            acc[mi][ni], 0, 0, 0);

    __syncthreads();
  }

#pragma unroll
  for (int mi = 0; mi < 4; ++mi)
#pragma unroll
    for (int ni = 0; ni < 4; ++ni)
#pragma unroll
      for (int r = 0; r < 4; ++r) {
        int row = mt * BM + wm + mi * 16 + quad * 4 + r;
        int col = nt * BN + wn + ni * 16 + lm;
        atomicAdd(&out[(size_t)row * OUT_DIM + col], acc[mi][ni][r]);
      }
}

// ---- fallback (R1-exact): in-kernel scatter GEMM, known-good 663 us ----
template <bool USE_WB>
__global__ __launch_bounds__(256) void kan_gemm(const float* __restrict__ x,
                                                const unsigned short* __restrict__ wb,
                                                const float* __restrict__ sw,
                                                const float* __restrict__ bs,
                                                float* __restrict__ out) {
  __shared__ __align__(16) unsigned short As[BM * BKPA];
  __shared__ __align__(16) unsigned short Ws[BN * BKPA];

  const int tid = threadIdx.x;
  const int mt = blockIdx.x, nt = blockIdx.y, kc = blockIdx.z;
  const int sb = tid & 127;
  const int shalf = tid >> 7;
  const int klo = shalf * 16;
  const int wrow = tid >> 1;
  const int whal = tid & 1;
  const int lane = tid & 63;
  const int wid = tid >> 6;
  const int wm = (wid & 1) * 64;
  const int wn = (wid >> 1) * 64;
  const int lm = lane & 15;
  const int quad = lane >> 4;
  const int ko = quad * 8;

  f32x4 acc[4][4];
#pragma unroll
  for (int a = 0; a < 4; ++a)
#pragma unroll
    for (int b = 0; b < 4; ++b) acc[a][b] = f32x4{0.f, 0.f, 0.f, 0.f};

  const float* xrow = x + (size_t)(mt * BM + sb) * IN_DIM;

  for (int step = 0; step < NSTEP; ++step) {
    const int kbase = kc * KCH + step * BK;
    {
      uint4 z = make_uint4(0, 0, 0, 0);
      uint4* az = (uint4*)(&As[sb * BKPA + klo]);
      az[0] = z;
      az[1] = z;
    }
    {
      const int ilo = kbase / KPI;
      const int ihi = (kbase + BK - 1) / KPI;
      for (int ii = ilo; ii <= ihi; ++ii) {
        float xv = xrow[ii];
        float xn = fminf(fmaxf(xv, -0.99f), 0.99f);
        float u = (xn + 1.0f) * 17.0f;
        float sf = floorf(u);
        int s = (int)sf;
        float f = u - sf, g = 1.0f - f;
        float f2 = f * f, g2 = g * g;
        float v0 = g2 * g * (1.f / 6.f);
        float v1 = 0.66666667f - f2 + 0.5f * f2 * f;
        float v2 = 0.66666667f - g2 + 0.5f * g2 * g;
        float v3 = f2 * f * (1.f / 6.f);
        float sig = xn / (1.0f + __expf(-xn));
        const int kb0 = ii * KPI - kbase;
#pragma unroll
        for (int t = 0; t < 4; ++t) {
          int c = s - 1 + t;
          float v = (t == 0) ? v0 : (t == 1) ? v1 : (t == 2) ? v2 : v3;
          int kq = kb0 + c;
          if (c >= 0 && c < NC && kq >= klo && kq < klo + 16)
            As[sb * BKPA + kq] = f2bf(v);
        }
        int kqb = kb0 + NC;
        if (kqb >= klo && kqb < klo + 16) As[sb * BKPA + kqb] = f2bf(sig);
      }
    }
    if (USE_WB) {
      const unsigned short* src = wb + (size_t)(nt * BN + wrow) * KTOT + kbase + whal * 16;
      uint4 w0 = ((const uint4*)src)[0];
      uint4 w1 = ((const uint4*)src)[1];
      uint4* wd = (uint4*)(&Ws[wrow * BKPA + whal * 16]);
      wd[0] = w0;
      wd[1] = w1;
    } else {
      const int j = nt * BN + wrow;
      unsigned int p[8];
#pragma unroll
      for (int q = 0; q < 8; ++q) {
        unsigned int lohi = 0;
#pragma unroll
        for (int h = 0; h < 2; ++h) {
          int k = kbase + whal * 16 + q * 2 + h;
          int i = k / KPI;
          int c = k - i * KPI;
          float v = (c < NC) ? sw[(size_t)i * (OUT_DIM * NC) + (size_t)j * NC + c]
                             : bs[(size_t)i * OUT_DIM + j];
          lohi |= ((unsigned int)f2bf(v)) << (16 * h);
        }
        p[q] = lohi;
      }
      uint4* wd = (uint4*)(&Ws[wrow * BKPA + whal * 16]);
      wd[0] = make_uint4(p[0], p[1], p[2], p[3]);
      wd[1] = make_uint4(p[4], p[5], p[6], p[7]);
    }

    __syncthreads();

    uint4 af[4], bfr[4];
#pragma unroll
    for (int mi = 0; mi < 4; ++mi)
      af[mi] = *(const uint4*)(&As[(wm + mi * 16 + lm) * BKPA + ko]);
#pragma unroll
    for (int ni = 0; ni < 4; ++ni)
      bfr[ni] = *(const uint4*)(&Ws[(wn + ni * 16 + lm) * BKPA + ko]);
#pragma unroll
    for (int mi = 0; mi < 4; ++mi)
#pragma unroll
      for (int ni = 0; ni < 4; ++ni)
        acc[mi][ni] = __builtin_amdgcn_mfma_f32_16x16x32_bf16(
            __builtin_bit_cast(bf16x8, af[mi]), __builtin_bit_cast(bf16x8, bfr[ni]),
            acc[mi][ni], 0, 0, 0);

    __syncthreads();
  }

#pragma unroll
  for (int mi = 0; mi < 4; ++mi)
#pragma unroll
    for (int ni = 0; ni < 4; ++ni)
#pragma unroll
      for (int r = 0; r < 4; ++r) {
        int row = mt * BM + wm + mi * 16 + quad * 4 + r;
        int col = nt * BN + wn + ni * 16 + lm;
        atomicAdd(&out[(size_t)row * OUT_DIM + col], acc[mi][ni][r]);
      }
}

extern "C" void kernel_launch(void* const* d_in, const int* in_sizes, int n_in,
                              void* d_out, int out_size, void* d_ws, size_t ws_size,
                              hipStream_t stream) {
  const float* x = (const float*)d_in[0];
  const float* sw = (const float*)d_in[1];
  const float* bs = (const float*)d_in[2];
  float* out = (float*)d_out;

  hipMemsetAsync(d_out, 0, (size_t)MROWS * OUT_DIM * sizeof(float), stream);

  const size_t WB_BYTES = (size_t)OUT_DIM * KTOT * sizeof(unsigned short);  // 75.5 MB
  const size_t A_BYTES = (size_t)MROWS * KTOT * sizeof(unsigned short);     // 302 MB
  dim3 grid(MROWS / BM, OUT_DIM / BN, NSPLIT);

  if (ws_size >= WB_BYTES + A_BYTES) {
    unsigned short* wbp = (unsigned short*)d_ws;
    unsigned short* ap = (unsigned short*)((char*)d_ws + WB_BYTES);
    prep_wb<<<(IN_DIM * OUT_DIM) / 256, 256, 0, stream>>>(sw, bs, wbp);
    prep_a<<<(MROWS * IN_DIM) / 256, 256, 0, stream>>>(x, ap);
    kan_gemm_pre<<<grid, 256, 0, stream>>>(ap, wbp, out);
  } else if (ws_size >= WB_BYTES) {
    unsigned short* wbp = (unsigned short*)d_ws;
    prep_wb<<<(IN_DIM * OUT_DIM) / 256, 256, 0, stream>>>(sw, bs, wbp);
    kan_gemm<true><<<grid, 256, 0, stream>>>(x, wbp, sw, bs, out);
  } else {
    kan_gemm<false><<<grid, 256, 0, stream>>>(x, nullptr, sw, bs, out);
  }
}

// Round 4
// 833.051 us; speedup vs baseline: 4.8331x; 1.0259x over previous
//
#include <hip/hip_runtime.h>
#include <hip/hip_bf16.h>

// FastKANLayer as one bf16 MFMA GEMM: out[b,j] = A[b,k] @ Wb[k,j], k = i*36+c.
//   c<35: A = cubic B-spline basis (4-tap sparse), Wb = spline_weight[i,j,c]
//   c==35: A = silu(clip(x)),                      Wb = base_scale[i,j]
// M=4096, N=1024, K=36864. A precomputed bf16 (302 MB in d_ws), Wb bf16 (75.5 MB).
// R4: triple-buffered async K-loop — global_load_lds prefetch 1 step ahead,
// raw `s_waitcnt vmcnt(4) lgkmcnt(0); s_barrier` (ONE barrier/step, never
// vmcnt(0) except last iter). Rotation distance 3 => write of buf X at step s
// is separated from last read of X (step s-3) by the step s-1 barrier. R3 was
// latency-bound (MfmaUtil 22, VALU 19, 60% idle) on the vmcnt(0) barrier drain.
// R2 lesson: no __launch_bounds__ min-waves (spills the 64-reg accumulator).

#define IN_DIM 1024
#define OUT_DIM 1024
#define NC 35
#define KPI 36
#define KTOT (IN_DIM * KPI)      // 36864
#define MROWS 4096
#define BM 128
#define BN 128
#define BK 32
#define NSPLIT 4
#define KCH (KTOT / NSPLIT)      // 9216
#define NSTEP (KCH / BK)         // 288

#define BKPA 40                  // fallback kernel's padded As row

typedef __attribute__((ext_vector_type(8))) __bf16 bf16x8;
typedef __attribute__((ext_vector_type(4))) float f32x4;

__device__ __forceinline__ unsigned short f2bf(float f) {
  unsigned int u = __builtin_bit_cast(unsigned int, f);
  u = (u + 0x7FFFu + ((u >> 16) & 1u)) >> 16;   // RNE
  return (unsigned short)u;
}

// ---- prep: Wb[n][k] bf16, k = i*36 + c. Coalesced read via LDS stage. ----
// grid (IN_DIM, OUT_DIM/256); block (i, n-slab) reads 256*35 contiguous floats.
__global__ __launch_bounds__(256) void prep_wb(const float* __restrict__ sw,
                                               const float* __restrict__ bs,
                                               unsigned short* __restrict__ wb) {
  __shared__ float sb[256 * NC];                 // 35840 B
  const int tid = threadIdx.x;
  const int i = blockIdx.x;
  const int n0 = blockIdx.y * 256;
  const float* src = sw + ((size_t)i * OUT_DIM + n0) * NC;
  for (int t = tid; t < 256 * NC; t += 256) sb[t] = src[t];
  float bv = bs[(size_t)i * OUT_DIM + n0 + tid];
  __syncthreads();
  unsigned short v[KPI];
  const float* mine = sb + tid * NC;             // stride 35 (odd): 2-way alias, free
#pragma unroll
  for (int c = 0; c < NC; ++c) v[c] = f2bf(mine[c]);
  v[NC] = f2bf(bv);
  uint2* dst = (uint2*)(wb + (size_t)(n0 + tid) * KTOT + i * KPI);
#pragma unroll
  for (int w = 0; w < 9; ++w) {
    uint2 t2;
    t2.x = (unsigned)v[4 * w + 0] | ((unsigned)v[4 * w + 1] << 16);
    t2.y = (unsigned)v[4 * w + 2] | ((unsigned)v[4 * w + 3] << 16);
    dst[w] = t2;
  }
}

// ---- prep: A[b][k] bf16 basis matrix, 302 MB. ----
__global__ __launch_bounds__(256) void prep_a(const float* __restrict__ x,
                                              unsigned short* __restrict__ A) {
  __shared__ unsigned short buf[256 * KPI];      // 18432 B
  const int tid = threadIdx.x;
  const int id = blockIdx.x * 256 + tid;         // (b,i) flat
  float xv = x[id];
  float xn = fminf(fmaxf(xv, -0.99f), 0.99f);
  float u = (xn + 1.0f) * 17.0f;                 // 1/h = 17
  float sf = floorf(u);
  int s = (int)sf;
  float f = u - sf, g = 1.0f - f;
  float f2 = f * f, g2 = g * g;
  float v0 = g2 * g * (1.f / 6.f);
  float v1 = 0.66666667f - f2 + 0.5f * f2 * f;
  float v2 = 0.66666667f - g2 + 0.5f * g2 * g;
  float v3 = f2 * f * (1.f / 6.f);
  float sig = xn / (1.0f + __expf(-xn));

  unsigned short* row = buf + tid * KPI;
  uint2 z = make_uint2(0, 0);
  uint2* rz = (uint2*)row;
#pragma unroll
  for (int w = 0; w < 9; ++w) rz[w] = z;
#pragma unroll
  for (int t = 0; t < 4; ++t) {
    int c = s - 1 + t;
    float v = (t == 0) ? v0 : (t == 1) ? v1 : (t == 2) ? v2 : v3;
    if (c >= 0 && c < NC) row[c] = f2bf(v);
  }
  row[NC] = f2bf(sig);
  __syncthreads();
  uint2* gdst = (uint2*)(A + (size_t)blockIdx.x * (256 * KPI));
  const uint2* gsrc = (const uint2*)buf;
#pragma unroll
  for (int w = 0; w < 9; ++w) gdst[tid + w * 256] = gsrc[tid + w * 256];
}

// ---- fast GEMM: triple-buffered async K-loop, 1 raw barrier/step. ----
__global__ __launch_bounds__(256) void kan_gemm_db(const unsigned short* __restrict__ A,
                                                   const unsigned short* __restrict__ wb,
                                                   float* __restrict__ out) {
  __shared__ __align__(16) unsigned short As[3][BM * BK];   // 3 x 8 KB
  __shared__ __align__(16) unsigned short Ws[3][BN * BK];   // 3 x 8 KB

  const int tid = threadIdx.x;
  const int mt = blockIdx.x, nt = blockIdx.y, kc = blockIdx.z;

  const int lane = tid & 63;
  const int wid = tid >> 6;
  const int wm = (wid & 1) * 64;
  const int wn = (wid >> 1) * 64;
  const int lm = lane & 15;
  const int quad = lane >> 4;
  const int ko = quad * 8;

  // staging lane mapping: one global_load_lds = 16 rows x 32 k (1 KB)
  const int wr16 = lane >> 2;          // row within 16-row chunk
  const int wkof = (lane & 3) * 8;     // k offset in ushorts (16 B / lane)

  f32x4 acc[4][4];
#pragma unroll
  for (int a = 0; a < 4; ++a)
#pragma unroll
    for (int b = 0; b < 4; ++b) acc[a][b] = f32x4{0.f, 0.f, 0.f, 0.f};

  const unsigned short* Ab =
      A + (size_t)(mt * BM + wid * 32 + wr16) * KTOT + kc * KCH + wkof;
  const unsigned short* Wg =
      wb + (size_t)(nt * BN + wid * 32 + wr16) * KTOT + kc * KCH + wkof;

  auto issue = [&](int buf, int koff) {
#pragma unroll
    for (int c = 0; c < 2; ++c)
      __builtin_amdgcn_global_load_lds(
          (const __attribute__((address_space(1))) unsigned int*)(Ab + (size_t)c * 16 * KTOT + koff),
          (__attribute__((address_space(3))) unsigned int*)(&As[buf][(wid * 32 + c * 16) * BK]),
          16, 0, 0);
#pragma unroll
    for (int c = 0; c < 2; ++c)
      __builtin_amdgcn_global_load_lds(
          (const __attribute__((address_space(1))) unsigned int*)(Wg + (size_t)c * 16 * KTOT + koff),
          (__attribute__((address_space(3))) unsigned int*)(&Ws[buf][(wid * 32 + c * 16) * BK]),
          16, 0, 0);
  };

  issue(0, 0);
  int cur = 0, nxt = 1;
  for (int step = 0; step < NSTEP; ++step) {
    if (step + 1 < NSTEP) {
      issue(nxt, (step + 1) * BK);
      // wait oldest 4 loads (this step's buffer); never drain the prefetch
      asm volatile("s_waitcnt vmcnt(4) lgkmcnt(0)\ns_barrier" ::: "memory");
    } else {
      asm volatile("s_waitcnt vmcnt(0) lgkmcnt(0)\ns_barrier" ::: "memory");
    }

    uint4 af[4], bfr[4];
#pragma unroll
    for (int mi = 0; mi < 4; ++mi)
      af[mi] = *(const uint4*)(&As[cur][(wm + mi * 16 + lm) * BK + ko]);
#pragma unroll
    for (int ni = 0; ni < 4; ++ni)
      bfr[ni] = *(const uint4*)(&Ws[cur][(wn + ni * 16 + lm) * BK + ko]);
#pragma unroll
    for (int mi = 0; mi < 4; ++mi)
#pragma unroll
      for (int ni = 0; ni < 4; ++ni)
        acc[mi][ni] = __builtin_amdgcn_mfma_f32_16x16x32_bf16(
            __builtin_bit_cast(bf16x8, af[mi]), __builtin_bit_cast(bf16x8, bfr[ni]),
            acc[mi][ni], 0, 0, 0);

    cur = nxt;
    nxt = (nxt == 2) ? 0 : nxt + 1;
  }

#pragma unroll
  for (int mi = 0; mi < 4; ++mi)
#pragma unroll
    for (int ni = 0; ni < 4; ++ni)
#pragma unroll
      for (int r = 0; r < 4; ++r) {
        int row = mt * BM + wm + mi * 16 + quad * 4 + r;
        int col = nt * BN + wn + ni * 16 + lm;
        atomicAdd(&out[(size_t)row * OUT_DIM + col], acc[mi][ni][r]);
      }
}

// ---- fallback (R1-exact): in-kernel scatter GEMM, known-good ----
template <bool USE_WB>
__global__ __launch_bounds__(256) void kan_gemm(const float* __restrict__ x,
                                                const unsigned short* __restrict__ wb,
                                                const float* __restrict__ sw,
                                                const float* __restrict__ bs,
                                                float* __restrict__ out) {
  __shared__ __align__(16) unsigned short As[BM * BKPA];
  __shared__ __align__(16) unsigned short Wsm[BN * BKPA];

  const int tid = threadIdx.x;
  const int mt = blockIdx.x, nt = blockIdx.y, kc = blockIdx.z;
  const int sb = tid & 127;
  const int shalf = tid >> 7;
  const int klo = shalf * 16;
  const int wrow = tid >> 1;
  const int whal = tid & 1;
  const int lane = tid & 63;
  const int wid = tid >> 6;
  const int wm = (wid & 1) * 64;
  const int wn = (wid >> 1) * 64;
  const int lm = lane & 15;
  const int quad = lane >> 4;
  const int ko = quad * 8;

  f32x4 acc[4][4];
#pragma unroll
  for (int a = 0; a < 4; ++a)
#pragma unroll
    for (int b = 0; b < 4; ++b) acc[a][b] = f32x4{0.f, 0.f, 0.f, 0.f};

  const float* xrow = x + (size_t)(mt * BM + sb) * IN_DIM;

  for (int step = 0; step < NSTEP; ++step) {
    const int kbase = kc * KCH + step * BK;
    {
      uint4 z = make_uint4(0, 0, 0, 0);
      uint4* az = (uint4*)(&As[sb * BKPA + klo]);
      az[0] = z;
      az[1] = z;
    }
    {
      const int ilo = kbase / KPI;
      const int ihi = (kbase + BK - 1) / KPI;
      for (int ii = ilo; ii <= ihi; ++ii) {
        float xv = xrow[ii];
        float xn = fminf(fmaxf(xv, -0.99f), 0.99f);
        float u = (xn + 1.0f) * 17.0f;
        float sf = floorf(u);
        int s = (int)sf;
        float f = u - sf, g = 1.0f - f;
        float f2 = f * f, g2 = g * g;
        float v0 = g2 * g * (1.f / 6.f);
        float v1 = 0.66666667f - f2 + 0.5f * f2 * f;
        float v2 = 0.66666667f - g2 + 0.5f * g2 * g;
        float v3 = f2 * f * (1.f / 6.f);
        float sig = xn / (1.0f + __expf(-xn));
        const int kb0 = ii * KPI - kbase;
#pragma unroll
        for (int t = 0; t < 4; ++t) {
          int c = s - 1 + t;
          float v = (t == 0) ? v0 : (t == 1) ? v1 : (t == 2) ? v2 : v3;
          int kq = kb0 + c;
          if (c >= 0 && c < NC && kq >= klo && kq < klo + 16)
            As[sb * BKPA + kq] = f2bf(v);
        }
        int kqb = kb0 + NC;
        if (kqb >= klo && kqb < klo + 16) As[sb * BKPA + kqb] = f2bf(sig);
      }
    }
    if (USE_WB) {
      const unsigned short* src = wb + (size_t)(nt * BN + wrow) * KTOT + kbase + whal * 16;
      uint4 w0 = ((const uint4*)src)[0];
      uint4 w1 = ((const uint4*)src)[1];
      uint4* wd = (uint4*)(&Wsm[wrow * BKPA + whal * 16]);
      wd[0] = w0;
      wd[1] = w1;
    } else {
      const int j = nt * BN + wrow;
      unsigned int p[8];
#pragma unroll
      for (int q = 0; q < 8; ++q) {
        unsigned int lohi = 0;
#pragma unroll
        for (int h = 0; h < 2; ++h) {
          int k = kbase + whal * 16 + q * 2 + h;
          int i = k / KPI;
          int c = k - i * KPI;
          float v = (c < NC) ? sw[(size_t)i * (OUT_DIM * NC) + (size_t)j * NC + c]
                             : bs[(size_t)i * OUT_DIM + j];
          lohi |= ((unsigned int)f2bf(v)) << (16 * h);
        }
        p[q] = lohi;
      }
      uint4* wd = (uint4*)(&Wsm[wrow * BKPA + whal * 16]);
      wd[0] = make_uint4(p[0], p[1], p[2], p[3]);
      wd[1] = make_uint4(p[4], p[5], p[6], p[7]);
    }

    __syncthreads();

    uint4 af[4], bfr[4];
#pragma unroll
    for (int mi = 0; mi < 4; ++mi)
      af[mi] = *(const uint4*)(&As[(wm + mi * 16 + lm) * BKPA + ko]);
#pragma unroll
    for (int ni = 0; ni < 4; ++ni)
      bfr[ni] = *(const uint4*)(&Wsm[(wn + ni * 16 + lm) * BKPA + ko]);
#pragma unroll
    for (int mi = 0; mi < 4; ++mi)
#pragma unroll
      for (int ni = 0; ni < 4; ++ni)
        acc[mi][ni] = __builtin_amdgcn_mfma_f32_16x16x32_bf16(
            __builtin_bit_cast(bf16x8, af[mi]), __builtin_bit_cast(bf16x8, bfr[ni]),
            acc[mi][ni], 0, 0, 0);

    __syncthreads();
  }

#pragma unroll
  for (int mi = 0; mi < 4; ++mi)
#pragma unroll
    for (int ni = 0; ni < 4; ++ni)
#pragma unroll
      for (int r = 0; r < 4; ++r) {
        int row = mt * BM + wm + mi * 16 + quad * 4 + r;
        int col = nt * BN + wn + ni * 16 + lm;
        atomicAdd(&out[(size_t)row * OUT_DIM + col], acc[mi][ni][r]);
      }
}

extern "C" void kernel_launch(void* const* d_in, const int* in_sizes, int n_in,
                              void* d_out, int out_size, void* d_ws, size_t ws_size,
                              hipStream_t stream) {
  const float* x = (const float*)d_in[0];
  const float* sw = (const float*)d_in[1];
  const float* bs = (const float*)d_in[2];
  float* out = (float*)d_out;

  hipMemsetAsync(d_out, 0, (size_t)MROWS * OUT_DIM * sizeof(float), stream);

  const size_t WB_BYTES = (size_t)OUT_DIM * KTOT * sizeof(unsigned short);  // 75.5 MB
  const size_t A_BYTES = (size_t)MROWS * KTOT * sizeof(unsigned short);     // 302 MB
  dim3 grid(MROWS / BM, OUT_DIM / BN, NSPLIT);

  if (ws_size >= WB_BYTES + A_BYTES) {
    unsigned short* wbp = (unsigned short*)d_ws;
    unsigned short* ap = (unsigned short*)((char*)d_ws + WB_BYTES);
    prep_wb<<<dim3(IN_DIM, OUT_DIM / 256), 256, 0, stream>>>(sw, bs, wbp);
    prep_a<<<(MROWS * IN_DIM) / 256, 256, 0, stream>>>(x, ap);
    kan_gemm_db<<<grid, 256, 0, stream>>>(ap, wbp, out);
  } else if (ws_size >= WB_BYTES) {
    unsigned short* wbp = (unsigned short*)d_ws;
    prep_wb<<<dim3(IN_DIM, OUT_DIM / 256), 256, 0, stream>>>(sw, bs, wbp);
    kan_gemm<true><<<grid, 256, 0, stream>>>(x, wbp, sw, bs, out);
  } else {
    kan_gemm<false><<<grid, 256, 0, stream>>>(x, nullptr, sw, bs, out);
  }
}

// Round 5
// 717.732 us; speedup vs baseline: 5.6096x; 1.1607x over previous
//
#include <hip/hip_runtime.h>
#include <hip/hip_bf16.h>

// FastKANLayer as one bf16 MFMA GEMM: out[b,j] = A[b,k] @ Wb[k,j], k = i*36+c.
//   c<35: A = cubic B-spline basis (4-tap sparse), Wb = spline_weight[i,j,c]
//   c==35: A = silu(clip(x)),                      Wb = base_scale[i,j]
// M=4096, N=1024, K=36864.
// R5: evidence says we're L3->XCD link-BW bound (~8.6 TB/s aggregate; R3 and
// R4's very different pipelines landed at the same 560-574 us). So:
//  - BM=BN=256 (512 thr, 8 waves, 128 acc regs/lane): tile traffic
//    A*4 + Wb*16 = 2.42 GB, half of the 128x128 tiling.
//  - A2/W2 stored pre-swizzled as the LDS tile image [w][row][32k]: every
//    global_load_lds is a contiguous 1KB chunk; prep writes are 64B/thread
//    coalesced (old prep_wb wrote 8B at 72KB stride - DRAM-hostile).
//  - Triple-buffered K-loop, vmcnt(4) + raw barrier (R4 structure).
// R2 lesson: no __launch_bounds__ min-waves (spills the accumulator).

#define IN_DIM 1024
#define OUT_DIM 1024
#define NC 35
#define KPI 36
#define KTOT (IN_DIM * KPI)      // 36864
#define NW (KTOT / 32)           // 1152 k-windows of 32
#define MROWS 4096
#define BM 256
#define BN 256
#define BK 32
#define NSPLIT 4
#define WPC (NW / NSPLIT)        // 288 windows per kc chunk

typedef __attribute__((ext_vector_type(8))) __bf16 bf16x8;
typedef __attribute__((ext_vector_type(4))) float f32x4;

__device__ __forceinline__ unsigned short f2bf(float f) {
  unsigned int u = __builtin_bit_cast(unsigned int, f);
  u = (u + 0x7FFFu + ((u >> 16) & 1u)) >> 16;   // RNE
  return (unsigned short)u;
}

// ---- prep: W2[w][n][32] bf16 (LDS tile image). 75.5 MB. ----
// block = (w-window, 256-n slab): coalesced slab reads, 64B/thread writes.
__global__ __launch_bounds__(256) void prep_w(const float* __restrict__ sw,
                                              const float* __restrict__ bs,
                                              unsigned short* __restrict__ w2) {
  __shared__ float sbuf[2][256 * NC];            // 71.7 KB
  const int tid = threadIdx.x;
  const int w = blockIdx.x;
  const int n0 = blockIdx.y * 256;
  const int k0 = w * 32;
  const int i0 = k0 / KPI;
  const int i1 = (k0 + 31) / KPI;                // i0 or i0+1
  const int iq[2] = {i0, i1};
  float bsv[2];
#pragma unroll
  for (int q = 0; q < 2; ++q) {
    const float* src = sw + ((size_t)iq[q] * OUT_DIM + n0) * NC;
    for (int t = tid; t < 256 * NC; t += 256) sbuf[q][t] = src[t];
    bsv[q] = bs[(size_t)iq[q] * OUT_DIM + n0 + tid];
  }
  __syncthreads();
  unsigned short v[32];
#pragma unroll
  for (int kk = 0; kk < 32; ++kk) {
    int k = k0 + kk;
    int q = (k >= (i0 + 1) * KPI) ? 1 : 0;
    int c = k - iq[q] * KPI;
    float f = (c < NC) ? sbuf[q][tid * NC + c] : bsv[q];
    v[kk] = f2bf(f);
  }
  uint4* dst = (uint4*)(w2 + ((size_t)w * OUT_DIM + n0 + tid) * 32);
#pragma unroll
  for (int j = 0; j < 4; ++j) {
    uint4 t4;
    t4.x = (unsigned)v[8 * j + 0] | ((unsigned)v[8 * j + 1] << 16);
    t4.y = (unsigned)v[8 * j + 2] | ((unsigned)v[8 * j + 3] << 16);
    t4.z = (unsigned)v[8 * j + 4] | ((unsigned)v[8 * j + 5] << 16);
    t4.w = (unsigned)v[8 * j + 6] | ((unsigned)v[8 * j + 7] << 16);
    dst[j] = t4;
  }
}

// ---- prep: A2[w][b][32] bf16 basis (LDS tile image). 302 MB. ----
__global__ __launch_bounds__(256) void prep_a2(const float* __restrict__ x,
                                               unsigned short* __restrict__ a2) {
  const int tid = threadIdx.x;
  const int w = blockIdx.x;
  const int b = blockIdx.y * 256 + tid;
  const int k0 = w * 32;
  const int i0 = k0 / KPI;
  const int i1 = (k0 + 31) / KPI;
  const int iq[2] = {i0, i1};
  int si[2];
  float tv0[2], tv1[2], tv2[2], tv3[2], sg[2];
#pragma unroll
  for (int q = 0; q < 2; ++q) {
    float xv = x[(size_t)b * IN_DIM + iq[q]];    // column read; L3-served
    float xn = fminf(fmaxf(xv, -0.99f), 0.99f);
    float u = (xn + 1.0f) * 17.0f;               // 1/h = 17
    float sf = floorf(u);
    si[q] = (int)sf;
    float f = u - sf, g = 1.0f - f;
    float f2 = f * f, g2 = g * g;
    tv0[q] = g2 * g * (1.f / 6.f);
    tv1[q] = 0.66666667f - f2 + 0.5f * f2 * f;
    tv2[q] = 0.66666667f - g2 + 0.5f * g2 * g;
    tv3[q] = f2 * f * (1.f / 6.f);
    sg[q] = xn / (1.0f + __expf(-xn));
  }
  unsigned short v[32];
#pragma unroll
  for (int kk = 0; kk < 32; ++kk) {
    int k = k0 + kk;
    int q = (k >= (i0 + 1) * KPI) ? 1 : 0;
    int c = k - iq[q] * KPI;
    float val;
    if (c == NC) {
      val = sg[q];
    } else {
      int rel = c - (si[q] - 1);
      val = (rel == 0) ? tv0[q]
          : (rel == 1) ? tv1[q]
          : (rel == 2) ? tv2[q]
          : (rel == 3) ? tv3[q] : 0.0f;
    }
    v[kk] = f2bf(val);
  }
  uint4* dst = (uint4*)(a2 + ((size_t)w * MROWS + b) * 32);
#pragma unroll
  for (int j = 0; j < 4; ++j) {
    uint4 t4;
    t4.x = (unsigned)v[8 * j + 0] | ((unsigned)v[8 * j + 1] << 16);
    t4.y = (unsigned)v[8 * j + 2] | ((unsigned)v[8 * j + 3] << 16);
    t4.z = (unsigned)v[8 * j + 4] | ((unsigned)v[8 * j + 5] << 16);
    t4.w = (unsigned)v[8 * j + 6] | ((unsigned)v[8 * j + 7] << 16);
    dst[j] = t4;
  }
}

// ---- fast GEMM: 256x256 tile, 8 waves, triple-buffered async K-loop. ----
__global__ __launch_bounds__(512) void kan_gemm3(const unsigned short* __restrict__ A2,
                                                 const unsigned short* __restrict__ W2,
                                                 float* __restrict__ out) {
  __shared__ __align__(16) unsigned short As[3][BM * BK];   // 3 x 16 KB
  __shared__ __align__(16) unsigned short Ws[3][BN * BK];   // 3 x 16 KB

  const int tid = threadIdx.x;
  const int mt = blockIdx.x, nt = blockIdx.y, kc = blockIdx.z;

  const int lane = tid & 63;
  const int wid = tid >> 6;                      // 0..7
  const int wm = (wid & 3) * 64;                 // 4 m-wave rows
  const int wn = (wid >> 2) * 128;               // 2 n-wave cols
  const int lm = lane & 15;
  const int quad = lane >> 4;
  const int ko = quad * 8;

  f32x4 acc[4][8];
#pragma unroll
  for (int a = 0; a < 4; ++a)
#pragma unroll
    for (int b = 0; b < 8; ++b) acc[a][b] = f32x4{0.f, 0.f, 0.f, 0.f};

  // staging: wave wid owns 16-row chunks g = 2*wid, 2*wid+1 of both tiles.
  // Each global_load_lds: contiguous 1KB (16 rows x 32 k), lane*16B.
  const unsigned short* Abase = A2 + (size_t)(mt * BM) * 32 + lane * 8;
  const unsigned short* Wbase = W2 + (size_t)(nt * BN) * 32 + lane * 8;

  auto issue = [&](int buf, int w) {
    const size_t aoff = (size_t)w * (MROWS * 32);
    const size_t woff = (size_t)w * (OUT_DIM * 32);
#pragma unroll
    for (int c = 0; c < 2; ++c) {
      const int g = wid * 2 + c;
      __builtin_amdgcn_global_load_lds(
          (const __attribute__((address_space(1))) unsigned int*)(Abase + aoff + (size_t)g * 512),
          (__attribute__((address_space(3))) unsigned int*)(&As[buf][g * 512]),
          16, 0, 0);
      __builtin_amdgcn_global_load_lds(
          (const __attribute__((address_space(1))) unsigned int*)(Wbase + woff + (size_t)g * 512),
          (__attribute__((address_space(3))) unsigned int*)(&Ws[buf][g * 512]),
          16, 0, 0);
    }
  };

  issue(0, kc * WPC);
  int cur = 0, nxt = 1;
  for (int step = 0; step < WPC; ++step) {
    if (step + 1 < WPC) {
      issue(nxt, kc * WPC + step + 1);
      // wait this step's 4 loads only; prefetch (newest 4) stays in flight
      asm volatile("s_waitcnt vmcnt(4) lgkmcnt(0)\ns_barrier" ::: "memory");
    } else {
      asm volatile("s_waitcnt vmcnt(0) lgkmcnt(0)\ns_barrier" ::: "memory");
    }

    uint4 af[4];
#pragma unroll
    for (int mi = 0; mi < 4; ++mi)
      af[mi] = *(const uint4*)(&As[cur][(wm + mi * 16 + lm) * BK + ko]);
#pragma unroll
    for (int h = 0; h < 2; ++h) {
      uint4 bfr[4];
#pragma unroll
      for (int nj = 0; nj < 4; ++nj)
        bfr[nj] = *(const uint4*)(&Ws[cur][(wn + h * 64 + nj * 16 + lm) * BK + ko]);
#pragma unroll
      for (int mi = 0; mi < 4; ++mi)
#pragma unroll
        for (int nj = 0; nj < 4; ++nj)
          acc[mi][h * 4 + nj] = __builtin_amdgcn_mfma_f32_16x16x32_bf16(
              __builtin_bit_cast(bf16x8, af[mi]), __builtin_bit_cast(bf16x8, bfr[nj]),
              acc[mi][h * 4 + nj], 0, 0, 0);
    }

    cur = nxt;
    nxt = (nxt == 2) ? 0 : nxt + 1;
  }

  // epilogue: C/D layout col=lane&15 (n), row=quad*4+reg (m); split-K atomics
#pragma unroll
  for (int mi = 0; mi < 4; ++mi)
#pragma unroll
    for (int ni = 0; ni < 8; ++ni)
#pragma unroll
      for (int r = 0; r < 4; ++r) {
        int row = mt * BM + wm + mi * 16 + quad * 4 + r;
        int col = nt * BN + wn + ni * 16 + lm;
        atomicAdd(&out[(size_t)row * OUT_DIM + col], acc[mi][ni][r]);
      }
}

// ================= fallback path (R1-proven), used only if ws too small ====
#define FB_BM 128
#define FB_BN 128
#define FB_BKPA 40
#define FB_KCH 9216
#define FB_NSTEP 288

__global__ __launch_bounds__(256) void prep_wb_fb(const float* __restrict__ sw,
                                                  const float* __restrict__ bs,
                                                  unsigned short* __restrict__ wb) {
  int id = blockIdx.x * 256 + threadIdx.x;
  int i = id & (IN_DIM - 1);
  int n = id >> 10;
  const float* s = sw + (size_t)i * (OUT_DIM * NC) + (size_t)n * NC;
  unsigned short v[KPI];
#pragma unroll
  for (int c = 0; c < NC; ++c) v[c] = f2bf(s[c]);
  v[NC] = f2bf(bs[(size_t)i * OUT_DIM + n]);
  uint2* dst = (uint2*)(wb + (size_t)n * KTOT + (size_t)i * KPI);
#pragma unroll
  for (int w = 0; w < 9; ++w) {
    uint2 t;
    t.x = (unsigned)v[4 * w + 0] | ((unsigned)v[4 * w + 1] << 16);
    t.y = (unsigned)v[4 * w + 2] | ((unsigned)v[4 * w + 3] << 16);
    dst[w] = t;
  }
}

template <bool USE_WB>
__global__ __launch_bounds__(256) void kan_gemm_fb(const float* __restrict__ x,
                                                   const unsigned short* __restrict__ wb,
                                                   const float* __restrict__ sw,
                                                   const float* __restrict__ bs,
                                                   float* __restrict__ out) {
  __shared__ __align__(16) unsigned short As[FB_BM * FB_BKPA];
  __shared__ __align__(16) unsigned short Wsm[FB_BN * FB_BKPA];

  const int tid = threadIdx.x;
  const int mt = blockIdx.x, nt = blockIdx.y, kc = blockIdx.z;
  const int sb = tid & 127;
  const int shalf = tid >> 7;
  const int klo = shalf * 16;
  const int wrow = tid >> 1;
  const int whal = tid & 1;
  const int lane = tid & 63;
  const int wid = tid >> 6;
  const int wm = (wid & 1) * 64;
  const int wn = (wid >> 1) * 64;
  const int lm = lane & 15;
  const int quad = lane >> 4;
  const int ko = quad * 8;

  f32x4 acc[4][4];
#pragma unroll
  for (int a = 0; a < 4; ++a)
#pragma unroll
    for (int b = 0; b < 4; ++b) acc[a][b] = f32x4{0.f, 0.f, 0.f, 0.f};

  const float* xrow = x + (size_t)(mt * FB_BM + sb) * IN_DIM;

  for (int step = 0; step < FB_NSTEP; ++step) {
    const int kbase = kc * FB_KCH + step * BK;
    {
      uint4 z = make_uint4(0, 0, 0, 0);
      uint4* az = (uint4*)(&As[sb * FB_BKPA + klo]);
      az[0] = z;
      az[1] = z;
    }
    {
      const int ilo = kbase / KPI;
      const int ihi = (kbase + BK - 1) / KPI;
      for (int ii = ilo; ii <= ihi; ++ii) {
        float xv = xrow[ii];
        float xn = fminf(fmaxf(xv, -0.99f), 0.99f);
        float u = (xn + 1.0f) * 17.0f;
        float sf = floorf(u);
        int s = (int)sf;
        float f = u - sf, g = 1.0f - f;
        float f2 = f * f, g2 = g * g;
        float v0 = g2 * g * (1.f / 6.f);
        float v1 = 0.66666667f - f2 + 0.5f * f2 * f;
        float v2 = 0.66666667f - g2 + 0.5f * g2 * g;
        float v3 = f2 * f * (1.f / 6.f);
        float sig = xn / (1.0f + __expf(-xn));
        const int kb0 = ii * KPI - kbase;
#pragma unroll
        for (int t = 0; t < 4; ++t) {
          int c = s - 1 + t;
          float v = (t == 0) ? v0 : (t == 1) ? v1 : (t == 2) ? v2 : v3;
          int kq = kb0 + c;
          if (c >= 0 && c < NC && kq >= klo && kq < klo + 16)
            As[sb * FB_BKPA + kq] = f2bf(v);
        }
        int kqb = kb0 + NC;
        if (kqb >= klo && kqb < klo + 16) As[sb * FB_BKPA + kqb] = f2bf(sig);
      }
    }
    if (USE_WB) {
      const unsigned short* src = wb + (size_t)(nt * FB_BN + wrow) * KTOT + kbase + whal * 16;
      uint4 w0 = ((const uint4*)src)[0];
      uint4 w1 = ((const uint4*)src)[1];
      uint4* wd = (uint4*)(&Wsm[wrow * FB_BKPA + whal * 16]);
      wd[0] = w0;
      wd[1] = w1;
    } else {
      const int j = nt * FB_BN + wrow;
      unsigned int p[8];
#pragma unroll
      for (int q = 0; q < 8; ++q) {
        unsigned int lohi = 0;
#pragma unroll
        for (int h = 0; h < 2; ++h) {
          int k = kbase + whal * 16 + q * 2 + h;
          int i = k / KPI;
          int c = k - i * KPI;
          float v = (c < NC) ? sw[(size_t)i * (OUT_DIM * NC) + (size_t)j * NC + c]
                             : bs[(size_t)i * OUT_DIM + j];
          lohi |= ((unsigned int)f2bf(v)) << (16 * h);
        }
        p[q] = lohi;
      }
      uint4* wd = (uint4*)(&Wsm[wrow * FB_BKPA + whal * 16]);
      wd[0] = make_uint4(p[0], p[1], p[2], p[3]);
      wd[1] = make_uint4(p[4], p[5], p[6], p[7]);
    }

    __syncthreads();

    uint4 af[4], bfr[4];
#pragma unroll
    for (int mi = 0; mi < 4; ++mi)
      af[mi] = *(const uint4*)(&As[(wm + mi * 16 + lm) * FB_BKPA + ko]);
#pragma unroll
    for (int ni = 0; ni < 4; ++ni)
      bfr[ni] = *(const uint4*)(&Wsm[(wn + ni * 16 + lm) * FB_BKPA + ko]);
#pragma unroll
    for (int mi = 0; mi < 4; ++mi)
#pragma unroll
      for (int ni = 0; ni < 4; ++ni)
        acc[mi][ni] = __builtin_amdgcn_mfma_f32_16x16x32_bf16(
            __builtin_bit_cast(bf16x8, af[mi]), __builtin_bit_cast(bf16x8, bfr[ni]),
            acc[mi][ni], 0, 0, 0);

    __syncthreads();
  }

#pragma unroll
  for (int mi = 0; mi < 4; ++mi)
#pragma unroll
    for (int ni = 0; ni < 4; ++ni)
#pragma unroll
      for (int r = 0; r < 4; ++r) {
        int row = mt * FB_BM + wm + mi * 16 + quad * 4 + r;
        int col = nt * FB_BN + wn + ni * 16 + lm;
        atomicAdd(&out[(size_t)row * OUT_DIM + col], acc[mi][ni][r]);
      }
}

extern "C" void kernel_launch(void* const* d_in, const int* in_sizes, int n_in,
                              void* d_out, int out_size, void* d_ws, size_t ws_size,
                              hipStream_t stream) {
  const float* x = (const float*)d_in[0];
  const float* sw = (const float*)d_in[1];
  const float* bs = (const float*)d_in[2];
  float* out = (float*)d_out;

  hipMemsetAsync(d_out, 0, (size_t)MROWS * OUT_DIM * sizeof(float), stream);

  const size_t WB_BYTES = (size_t)NW * OUT_DIM * 32 * sizeof(unsigned short);  // 75.5 MB
  const size_t A_BYTES = (size_t)NW * MROWS * 32 * sizeof(unsigned short);     // 302 MB

  if (ws_size >= WB_BYTES + A_BYTES) {
    unsigned short* w2 = (unsigned short*)d_ws;
    unsigned short* a2 = (unsigned short*)((char*)d_ws + WB_BYTES);
    prep_w<<<dim3(NW, OUT_DIM / 256), 256, 0, stream>>>(sw, bs, w2);
    prep_a2<<<dim3(NW, MROWS / 256), 256, 0, stream>>>(x, a2);
    kan_gemm3<<<dim3(MROWS / BM, OUT_DIM / BN, NSPLIT), 512, 0, stream>>>(a2, w2, out);
  } else if (ws_size >= WB_BYTES) {
    unsigned short* wbp = (unsigned short*)d_ws;
    prep_wb_fb<<<(IN_DIM * OUT_DIM) / 256, 256, 0, stream>>>(sw, bs, wbp);
    kan_gemm_fb<true><<<dim3(32, 8, 4), 256, 0, stream>>>(x, wbp, sw, bs, out);
  } else {
    kan_gemm_fb<false><<<dim3(32, 8, 4), 256, 0, stream>>>(x, nullptr, sw, bs, out);
  }
}